// Round 3
// 1501.420 us; speedup vs baseline: 1.0632x; 1.0632x over previous
//
#include <hip/hip_runtime.h>
#include <stdint.h>

#define BATCH   8192
#define NTOT    4096
#define HID     256
#define NLAYERS 8
#define NMASK   2048
#define HALF    ((size_t)BATCH * NMASK)   // elements per checkerboard half

typedef unsigned short ushort_t;
typedef float  f32x4  __attribute__((ext_vector_type(4)));
typedef __bf16 bf16x8 __attribute__((ext_vector_type(8)));
typedef unsigned short u16x4 __attribute__((ext_vector_type(4)));

__device__ __forceinline__ unsigned short f2bf(float f) {
    union { float f; unsigned u; } v; v.f = f;
    unsigned r = v.u + 0x7FFFu + ((v.u >> 16) & 1u);
    return (unsigned short)(r >> 16);
}
__device__ __forceinline__ float bf2f(unsigned short h) {
    union { float f; unsigned u; } v; v.u = ((unsigned)h) << 16;
    return v.f;
}
__device__ __forceinline__ void split2(float f, unsigned short& hi, unsigned short& lo) {
    hi = f2bf(f);
    lo = f2bf(f - bf2f(hi));
}
// async global->LDS, 16B per lane. LDS dest must be lane-affine (base + lane*16).
__device__ __forceinline__ void async16(const void* g, void* l) {
    __builtin_amdgcn_global_load_lds(
        (const __attribute__((address_space(1))) unsigned int*)g,
        (__attribute__((address_space(3))) unsigned int*)l, 16, 0, 0);
}

// ---------------------------------------------------------------------------
// Weight transpose + bf16 hi/lo split: in [NL][K][N] fp32 -> out [NL][N][K]
// ---------------------------------------------------------------------------
__global__ __launch_bounds__(256) void split_transpose_kernel(
    const float* __restrict__ W,
    ushort_t* __restrict__ Whi, ushort_t* __restrict__ Wlo,
    int K, int N)
{
    __shared__ float tile[32][33];
    const int l  = blockIdx.z;
    const int k0 = blockIdx.x * 32;
    const int n0 = blockIdx.y * 32;
    const float* Wl = W + (size_t)l * K * N;
    const int tx = threadIdx.x & 31;
    const int ty = threadIdx.x >> 5;
#pragma unroll
    for (int it = 0; it < 4; ++it) {
        int r = ty + it * 8;
        tile[r][tx] = Wl[(size_t)(k0 + r) * N + (n0 + tx)];
    }
    __syncthreads();
    const size_t obase = (size_t)l * N * K;
#pragma unroll
    for (int it = 0; it < 4; ++it) {
        int r = ty + it * 8;
        float v = tile[tx][r];
        unsigned short hi, lo; split2(v, hi, lo);
        size_t oi = obase + (size_t)(n0 + r) * K + (k0 + tx);
        Whi[oi] = hi; Wlo[oi] = lo;
    }
}

// ---------------------------------------------------------------------------
// prep: z -> dense masked-ordered hi/lo splits for both checkerboard halves.
// half q at col(n,q) = 64*rsp + 2*c + ((rsp+q)&1), n = 32*rsp + c.
// ---------------------------------------------------------------------------
__global__ __launch_bounds__(256) void prep_split(
    const float* __restrict__ z,
    ushort_t* __restrict__ xsh, ushort_t* __restrict__ xsl)
{
    size_t f = (((size_t)blockIdx.x * 256) + threadIdx.x) * 4;  // pair base index
    int row = (int)(f >> 11);
    int n   = (int)(f & 2047);
    int sel = (n >> 5) & 1;                 // rsp parity (uniform over 4 pairs)
    const float4* zp = (const float4*)(z + (size_t)row * NTOT + 2 * (size_t)n);
    float4 z01 = zp[0], z23 = zp[1];
    float e[8] = {z01.x, z01.y, z01.z, z01.w, z23.x, z23.y, z23.z, z23.w};
    u16x4 ah, al, bh, bl;
#pragma unroll
    for (int i = 0; i < 4; ++i) {
        float c0 = e[2 * i], c1 = e[2 * i + 1];
        float a = sel ? c1 : c0;            // half 0
        float b = sel ? c0 : c1;            // half 1
        unsigned short h, l;
        split2(a, h, l); ah[i] = h; al[i] = l;
        split2(b, h, l); bh[i] = h; bl[i] = l;
    }
    size_t off = (size_t)row * NMASK + n;
    *(u16x4*)&xsh[off] = ah;        *(u16x4*)&xsl[off] = al;
    *(u16x4*)&xsh[HALF + off] = bh; *(u16x4*)&xsl[HALF + off] = bl;
}

// ---------------------------------------------------------------------------
// finalize: dense hi/lo splits (both halves) -> fp32 x in natural layout
// ---------------------------------------------------------------------------
__global__ __launch_bounds__(256) void finalize_x(
    const ushort_t* __restrict__ xsh, const ushort_t* __restrict__ xsl,
    float* __restrict__ xout)
{
    size_t f = (((size_t)blockIdx.x * 256) + threadIdx.x) * 4;
    int row = (int)(f >> 11);
    int n   = (int)(f & 2047);
    int sel = (n >> 5) & 1;
    size_t off = (size_t)row * NMASK + n;
    u16x4 ah = *(const u16x4*)&xsh[off],        al = *(const u16x4*)&xsl[off];
    u16x4 bh = *(const u16x4*)&xsh[HALF + off], bl = *(const u16x4*)&xsl[HALF + off];
    float o[8];
#pragma unroll
    for (int i = 0; i < 4; ++i) {
        float va = bf2f(ah[i]) + bf2f(al[i]);
        float vb = bf2f(bh[i]) + bf2f(bl[i]);
        o[2 * i]     = sel ? vb : va;
        o[2 * i + 1] = sel ? va : vb;
    }
    float* op = xout + (size_t)row * NTOT + 2 * (size_t)n;
    ((float4*)op)[0] = make_float4(o[0], o[1], o[2], o[3]);
    ((float4*)op)[1] = make_float4(o[4], o[5], o[6], o[7]);
}

// ---------------------------------------------------------------------------
// gemm_splitk: 128x128 tile, triple-bf16, K-tile 32, global_load_lds staging.
// MFMA operands SWAPPED (A-op = weight frag, B-op = data frag) so the C/D
// fragment holds 4 consecutive output cols per reg -> float4 stores.
// Stores raw fp32 partial to Pout + blockIdx.z * BATCH*HID.
// ---------------------------------------------------------------------------
__global__ __launch_bounds__(256) void gemm_splitk(
    const ushort_t* __restrict__ Ahi, const ushort_t* __restrict__ Alo, int lda,
    const ushort_t* __restrict__ Bhi, const ushort_t* __restrict__ Blo, int ldb,
    int nk,
    float* __restrict__ Pout)
{
    __shared__ __align__(16) ushort_t Ah[128 * 32], Al[128 * 32];
    __shared__ __align__(16) ushort_t Bh[128 * 32], Bl[128 * 32];

    const int t = threadIdx.x;
    const int row0 = blockIdx.x * 128;
    const int col0 = blockIdx.y * 128;
    const int k0   = blockIdx.z * nk * 32;
    const int w  = t >> 6, L = t & 63;
    const int q  = L >> 4, nl = L & 15;
    const int wr = w >> 1, wc = w & 1;

    f32x4 acc[4][4] = {};

    for (int kt = 0; kt < nk; ++kt) {
        const int kk = k0 + kt * 32;
#pragma unroll
        for (int pass = 0; pass < 2; ++pass) {
            const int chunk = t + pass * 256;
            const int r  = chunk >> 2;
            const int ko = (chunk & 3) * 8;
            async16(Ahi + (size_t)(row0 + r) * lda + kk + ko, (char*)Ah + chunk * 16);
            async16(Alo + (size_t)(row0 + r) * lda + kk + ko, (char*)Al + chunk * 16);
            async16(Bhi + (size_t)(col0 + r) * ldb + kk + ko, (char*)Bh + chunk * 16);
            async16(Blo + (size_t)(col0 + r) * ldb + kk + ko, (char*)Bl + chunk * 16);
        }
        __syncthreads();

        bf16x8 a_h[4], a_l[4];
#pragma unroll
        for (int mt = 0; mt < 4; ++mt) {
            const int r = wr * 64 + mt * 16 + nl;
            a_h[mt] = *(const bf16x8*)&Ah[r * 32 + q * 8];
            a_l[mt] = *(const bf16x8*)&Al[r * 32 + q * 8];
        }
#pragma unroll
        for (int nt = 0; nt < 4; ++nt) {
            const int c = wc * 64 + nt * 16 + nl;
            bf16x8 b_h = *(const bf16x8*)&Bh[c * 32 + q * 8];
            bf16x8 b_l = *(const bf16x8*)&Bl[c * 32 + q * 8];
#pragma unroll
            for (int mt = 0; mt < 4; ++mt) {
                // swapped: A-operand = weight frag (cols in regs), B-op = data frag
                acc[mt][nt] = __builtin_amdgcn_mfma_f32_16x16x32_bf16(b_h, a_h[mt], acc[mt][nt], 0, 0, 0);
                acc[mt][nt] = __builtin_amdgcn_mfma_f32_16x16x32_bf16(b_l, a_h[mt], acc[mt][nt], 0, 0, 0);
                acc[mt][nt] = __builtin_amdgcn_mfma_f32_16x16x32_bf16(b_h, a_l[mt], acc[mt][nt], 0, 0, 0);
            }
        }
        __syncthreads();
    }

    // D layout after swap: reg r -> col = col0+wc*64+nt*16+q*4+r, lane nl -> row
    float* out = Pout + (size_t)blockIdx.z * BATCH * HID;
#pragma unroll
    for (int mt = 0; mt < 4; ++mt) {
        const int row = row0 + wr * 64 + mt * 16 + nl;
#pragma unroll
        for (int nt = 0; nt < 4; ++nt) {
            const int col = col0 + wc * 64 + nt * 16 + q * 4;
            *(f32x4*)&out[(size_t)row * HID + col] = acc[mt][nt];
        }
    }
}

// ---------------------------------------------------------------------------
// combine split-K partials: O = leaky(sum_j P[j] + bias), hi/lo split store
// ---------------------------------------------------------------------------
__global__ __launch_bounds__(256) void combine_leaky(
    const float* __restrict__ P, int np, const float* __restrict__ bias,
    ushort_t* __restrict__ Ohi, ushort_t* __restrict__ Olo)
{
    size_t f = (((size_t)blockIdx.x * 256) + threadIdx.x) * 4;
    const int col = (int)(f & (HID - 1));
    float4 a = *(const float4*)&P[f];
    for (int j = 1; j < np; ++j) {
        float4 p = *(const float4*)&P[(size_t)j * BATCH * HID + f];
        a.x += p.x; a.y += p.y; a.z += p.z; a.w += p.w;
    }
    float4 bv = *(const float4*)&bias[col];
    float v[4] = {a.x + bv.x, a.y + bv.y, a.z + bv.z, a.w + bv.w};
    u16x4 h, l;
#pragma unroll
    for (int i = 0; i < 4; ++i) {
        float vv = v[i] > 0.f ? v[i] : 0.2f * v[i];
        unsigned short hh, ll; split2(vv, hh, ll);
        h[i] = hh; l[i] = ll;
    }
    *(u16x4*)&Ohi[f] = h;
    *(u16x4*)&Olo[f] = l;
}

// ---------------------------------------------------------------------------
// gemm3_update: st = h2 @ W3 + b3 for 128 rows x 128 s-cols (+ paired t-cols);
// s = 2*tanh(.); new = old*exp(s)+t written in place to the dense split buffer
// (half q1) -- which is also the next layer's gemm1 A operand. logdet += sum s.
// MFMA operands SWAPPED: regs hold 4 consecutive n -> u16x4 vector x-RMW.
// ---------------------------------------------------------------------------
__global__ __launch_bounds__(256, 2) void gemm3_update(
    const ushort_t* __restrict__ Ahi, const ushort_t* __restrict__ Alo,  // h2 splits [B][256]
    const ushort_t* __restrict__ Whi, const ushort_t* __restrict__ Wlo,  // W3 n-major [4096][256]
    const float* __restrict__ b3,                                        // [4096]
    ushort_t* __restrict__ xsh, ushort_t* __restrict__ xsl,              // [2][B][2048]
    float* __restrict__ logdet, int q1)
{
    __shared__ __align__(16) ushort_t Ah[128 * 32], Al[128 * 32];
    __shared__ __align__(16) ushort_t Bsh[128 * 32], Bsl[128 * 32];
    __shared__ __align__(16) ushort_t Bth[128 * 32], Btl[128 * 32];

    const int t = threadIdx.x;
    const int row0 = blockIdx.x * 128;
    const int n0   = blockIdx.y * 128;
    const int w  = t >> 6, L = t & 63;
    const int q  = L >> 4, nl = L & 15;
    const int wr = w >> 1, wc = w & 1;

    f32x4 accS[4][4] = {};
    f32x4 accT[4][4] = {};

    for (int kt = 0; kt < HID / 32; ++kt) {
        const int kk = kt * 32;
#pragma unroll
        for (int pass = 0; pass < 2; ++pass) {
            const int chunk = t + pass * 256;
            const int r  = chunk >> 2;
            const int ko = (chunk & 3) * 8;
            async16(Ahi + (size_t)(row0 + r) * HID + kk + ko, (char*)Ah + chunk * 16);
            async16(Alo + (size_t)(row0 + r) * HID + kk + ko, (char*)Al + chunk * 16);
            const size_t gs = (size_t)(n0 + r) * HID + kk + ko;
            async16(Whi + gs, (char*)Bsh + chunk * 16);
            async16(Wlo + gs, (char*)Bsl + chunk * 16);
            async16(Whi + (size_t)NMASK * HID + gs, (char*)Bth + chunk * 16);
            async16(Wlo + (size_t)NMASK * HID + gs, (char*)Btl + chunk * 16);
        }
        __syncthreads();

        bf16x8 a_h[4], a_l[4];
#pragma unroll
        for (int mt = 0; mt < 4; ++mt) {
            const int r = wr * 64 + mt * 16 + nl;
            a_h[mt] = *(const bf16x8*)&Ah[r * 32 + q * 8];
            a_l[mt] = *(const bf16x8*)&Al[r * 32 + q * 8];
        }
#pragma unroll
        for (int nt = 0; nt < 4; ++nt) {
            const int c = wc * 64 + nt * 16 + nl;
            bf16x8 bs_h = *(const bf16x8*)&Bsh[c * 32 + q * 8];
            bf16x8 bs_l = *(const bf16x8*)&Bsl[c * 32 + q * 8];
            bf16x8 bt_h = *(const bf16x8*)&Bth[c * 32 + q * 8];
            bf16x8 bt_l = *(const bf16x8*)&Btl[c * 32 + q * 8];
#pragma unroll
            for (int mt = 0; mt < 4; ++mt) {
                // swapped operands: regs hold n-dim, lanes hold batch rows
                accS[mt][nt] = __builtin_amdgcn_mfma_f32_16x16x32_bf16(bs_h, a_h[mt], accS[mt][nt], 0, 0, 0);
                accS[mt][nt] = __builtin_amdgcn_mfma_f32_16x16x32_bf16(bs_l, a_h[mt], accS[mt][nt], 0, 0, 0);
                accS[mt][nt] = __builtin_amdgcn_mfma_f32_16x16x32_bf16(bs_h, a_l[mt], accS[mt][nt], 0, 0, 0);
                accT[mt][nt] = __builtin_amdgcn_mfma_f32_16x16x32_bf16(bt_h, a_h[mt], accT[mt][nt], 0, 0, 0);
                accT[mt][nt] = __builtin_amdgcn_mfma_f32_16x16x32_bf16(bt_l, a_h[mt], accT[mt][nt], 0, 0, 0);
                accT[mt][nt] = __builtin_amdgcn_mfma_f32_16x16x32_bf16(bt_h, a_l[mt], accT[mt][nt], 0, 0, 0);
            }
        }
        __syncthreads();
    }

    // ---- epilogue ----
    // D layout after swap: reg r -> n = n0+wc*64+nt*16+q*4+r; lane nl -> row
    ushort_t* xh = xsh + (size_t)q1 * HALF;
    ushort_t* xl = xsl + (size_t)q1 * HALF;

    // biases depend only on nt (not mt): hoist as float4
    float4 bs4[4], bt4[4];
#pragma unroll
    for (int nt = 0; nt < 4; ++nt) {
        const int n = n0 + wc * 64 + nt * 16 + q * 4;
        bs4[nt] = *(const float4*)&b3[n];
        bt4[nt] = *(const float4*)&b3[n + NMASK];
    }

#pragma unroll
    for (int mt = 0; mt < 4; ++mt) {
        const int row = row0 + wr * 64 + mt * 16 + nl;
        float ldv = 0.f;
#pragma unroll
        for (int nt = 0; nt < 4; ++nt) {
            const int n = n0 + wc * 64 + nt * 16 + q * 4;
            const size_t off = (size_t)row * NMASK + n;
            u16x4 oh = *(const u16x4*)&xh[off];
            u16x4 ol = *(const u16x4*)&xl[off];
            const float* bsp = (const float*)&bs4[nt];
            const float* btp = (const float*)&bt4[nt];
            u16x4 nh, nlo;
#pragma unroll
            for (int r = 0; r < 4; ++r) {
                const float sv = accS[mt][nt][r] + bsp[r];
                // overflow-safe 2*tanh(sv) via fast exp
                const float e2 = __expf(-2.f * fabsf(sv));
                float th = __fdividef(1.f - e2, 1.f + e2);
                th = __builtin_copysignf(th, sv);
                const float s  = 2.f * th;
                const float es = __expf(s);
                const float old = bf2f(oh[r]) + bf2f(ol[r]);
                const float nv  = old * es + accT[mt][nt][r] + btp[r];
                unsigned short hh, ll; split2(nv, hh, ll);
                nh[r] = hh; nlo[r] = ll;
                ldv += s;
            }
            *(u16x4*)&xh[off] = nh;
            *(u16x4*)&xl[off] = nlo;
        }
        // lanes l, l^16, l^32, l^48 share the same row (row independent of q)
        ldv += __shfl_xor(ldv, 16);
        ldv += __shfl_xor(ldv, 32);
        if (q == 0)
            atomicAdd(&logdet[row], ldv);
    }
}

// ---------------------------------------------------------------------------
extern "C" void kernel_launch(void* const* d_in, const int* in_sizes, int n_in,
                              void* d_out, int out_size, void* d_ws, size_t ws_size,
                              hipStream_t stream)
{
    const float* z  = (const float*)d_in[0];
    const float* W1 = (const float*)d_in[1];
    const float* b1 = (const float*)d_in[2];
    const float* W2 = (const float*)d_in[3];
    const float* b2 = (const float*)d_in[4];
    const float* W3 = (const float*)d_in[5];
    const float* b3 = (const float*)d_in[6];

    float* xout   = (float*)d_out;
    float* logdet = xout + (size_t)BATCH * NTOT;

    // workspace layout (u16 elements, then fp32 partials) -- ~250 MB total
    ushort_t* ws = (ushort_t*)d_ws;
    size_t o = 0;
    ushort_t* W1h = ws + o; o += (size_t)NLAYERS * HID * NMASK;
    ushort_t* W1l = ws + o; o += (size_t)NLAYERS * HID * NMASK;
    ushort_t* W2h = ws + o; o += (size_t)NLAYERS * HID * HID;
    ushort_t* W2l = ws + o; o += (size_t)NLAYERS * HID * HID;
    ushort_t* W3h = ws + o; o += (size_t)NLAYERS * NTOT * HID;
    ushort_t* W3l = ws + o; o += (size_t)NLAYERS * NTOT * HID;
    ushort_t* h1h = ws + o; o += (size_t)BATCH * HID;
    ushort_t* h1l = ws + o; o += (size_t)BATCH * HID;
    ushort_t* h2h = ws + o; o += (size_t)BATCH * HID;
    ushort_t* h2l = ws + o; o += (size_t)BATCH * HID;
    ushort_t* xsh = ws + o; o += 2 * HALF;
    ushort_t* xsl = ws + o; o += 2 * HALF;
    float*    P   = (float*)(ws + o);   // [4][BATCH][HID] fp32 split-K partials

    hipMemsetAsync(logdet, 0, sizeof(float) * BATCH, stream);

    // weights: transpose to n-major + hi/lo split
    split_transpose_kernel<<<dim3(NMASK / 32, HID / 32, NLAYERS), 256, 0, stream>>>(
        W1, W1h, W1l, NMASK, HID);
    split_transpose_kernel<<<dim3(HID / 32, HID / 32, NLAYERS), 256, 0, stream>>>(
        W2, W2h, W2l, HID, HID);
    split_transpose_kernel<<<dim3(HID / 32, NTOT / 32, NLAYERS), 256, 0, stream>>>(
        W3, W3h, W3l, HID, NTOT);

    // z -> dense masked-ordered hi/lo splits for both halves
    prep_split<<<dim3((unsigned)(HALF / 4 / 256)), 256, 0, stream>>>(z, xsh, xsl);

    const unsigned cgrid = (unsigned)((size_t)BATCH * HID / 4 / 256);
    for (int i = 0; i < NLAYERS; ++i) {
        const int p  = i & 1;      // masked half
        const int q1 = 1 - p;      // updated half
        // gemm1 (split-K=4): P[ks] = xm @ W1  (M=8192,N=256,K=2048)
        gemm_splitk<<<dim3(BATCH / 128, HID / 128, 4), 256, 0, stream>>>(
            xsh + (size_t)p * HALF, xsl + (size_t)p * HALF, NMASK,
            W1h + (size_t)i * HID * NMASK, W1l + (size_t)i * HID * NMASK, NMASK,
            16, P);
        combine_leaky<<<cgrid, 256, 0, stream>>>(P, 4, b1 + (size_t)i * HID, h1h, h1l);
        // gemm2 (split-K=4): P[ks] = h1 @ W2  (K=256)
        gemm_splitk<<<dim3(BATCH / 128, HID / 128, 4), 256, 0, stream>>>(
            h1h, h1l, HID,
            W2h + (size_t)i * HID * HID, W2l + (size_t)i * HID * HID, HID,
            2, P);
        combine_leaky<<<cgrid, 256, 0, stream>>>(P, 4, b2 + (size_t)i * HID, h2h, h2l);
        // gemm3 + coupling update (writes next layer's masked splits in place)
        gemm3_update<<<dim3(BATCH / 128, NMASK / 128), 256, 0, stream>>>(
            h2h, h2l,
            W3h + (size_t)i * NTOT * HID, W3l + (size_t)i * NTOT * HID,
            b3 + (size_t)i * NTOT,
            xsh, xsl, logdet, q1);
    }

    finalize_x<<<dim3((unsigned)(HALF / 4 / 256)), 256, 0, stream>>>(xsh, xsl, xout);
}